// Round 15
// baseline (177.157 us; speedup 1.0000x reference)
//
#include <hip/hip_runtime.h>

#define IN_F 512
#define OUT_F 1024
#define K_ACTIVE 11  // ceil(0.01 * 1024) serial MP steps
#define K_IN 6       // ceil(0.01 * 512) kwta winners

// ---- w [1024][512] f32 -> wT [513][1024] f32 (row 512 = zeros, pad reads) ----
// wT is 2.1 MB: fits per-XCD L2 (4 MiB) together with w (2 MB). R6 measured fp64
// wT (4.2 MB) thrashing L2 -> 156 MB HBM fetch, +34 us. Keep f32.
__global__ __launch_bounds__(256) void transpose_w_kernel(const float* __restrict__ w,
                                                          float* __restrict__ wT) {
    __shared__ float tile[32][33];
    const int tx = threadIdx.x & 31;
    const int ty = threadIdx.x >> 5;  // 0..7
    const int i0 = blockIdx.x * 32;
    const int j0 = blockIdx.y * 32;
#pragma unroll
    for (int k = 0; k < 4; ++k)
        tile[ty + 8 * k][tx] = w[(size_t)(j0 + ty + 8 * k) * IN_F + (i0 + tx)];
    __syncthreads();
#pragma unroll
    for (int k = 0; k < 4; ++k)
        wT[(size_t)(i0 + ty + 8 * k) * OUT_F + (j0 + tx)] = tile[tx][ty + 8 * k];
}
__global__ void zero_row_f_kernel(float* __restrict__ wT) {
    wT[(size_t)IN_F * OUT_F + blockIdx.x * 256 + threadIdx.x] = 0.0f;
}

// ---- order-preserving fp64 -> u64 key, low bits carry reversed index ----
__device__ __forceinline__ unsigned long long pack_key(double v, unsigned rev,
                                                       unsigned long long mask) {
    unsigned long long b = (unsigned long long)__double_as_longlong(v);
    unsigned long long m =
        (unsigned long long)((long long)b >> 63) | 0x8000000000000000ull;
    unsigned long long u = b ^ m;  // monotonic total order
    return (u & ~mask) | (unsigned long long)rev;
}

// ---- monotonic u32 key from the f64 HIGH word ----
__device__ __forceinline__ unsigned hi_key(double v) {
    const int hi = __double2hiint(v);
    return (unsigned)hi ^ ((unsigned)(hi >> 31) | 0x80000000u);
}

// ---- wave max of u32 via DPP chain (bound_ctrl=true: invalid lanes -> 0) ----
template <int C>
__device__ __forceinline__ unsigned maxdpp(unsigned v) {
    unsigned t = (unsigned)__builtin_amdgcn_update_dpp(0, (int)v, C, 0xF, 0xF, true);
    return t > v ? t : v;
}
__device__ __forceinline__ unsigned wave_umax(unsigned v) {
    v = maxdpp<0x111>(v);  // row_shr:1
    v = maxdpp<0x112>(v);  // row_shr:2
    v = maxdpp<0x114>(v);  // row_shr:4
    v = maxdpp<0x118>(v);  // row_shr:8
    v = maxdpp<0x142>(v);  // row_bcast:15
    v = maxdpp<0x143>(v);  // row_bcast:31 -> lane 63 holds wave max
    return (unsigned)__builtin_amdgcn_readlane((int)v, 63);
}

// ---- exact wave max of u64 key (rare path): high32 chain + tie resolve ----
__device__ __forceinline__ unsigned long long wave_max_key(unsigned long long k) {
    const unsigned h = (unsigned)(k >> 32), l = (unsigned)k;
    const unsigned gh = wave_umax(h);
    const unsigned long long tied = __ballot(h == gh);
    unsigned gl;
    if (__popcll(tied) == 1) {
        gl = (unsigned)__builtin_amdgcn_readlane((int)l,
                                                 (int)__ffsll((long long)tied) - 1);
    } else {
        gl = wave_umax((h == gh) ? l : 0u);
    }
    return ((unsigned long long)gh << 32) | gl;
}

// MODE0 fallbacks (no workspace): strided gathers from row-major w
__device__ __forceinline__ void half_add0(double* rh, const float* __restrict__ w,
                                          int i, int lane, int wv) {
#pragma unroll
    for (int s = 0; s < 8; ++s) {
        const int j = (wv << 9) | ((s >> 2) << 8) | (lane << 2) | (s & 3);
        rh[s] += (double)w[(size_t)j * IN_F + i];
    }
}
__device__ __forceinline__ void half_axpy0(double* rh, const float* __restrict__ w,
                                           int i, double sgn, int lane, int wv) {
#pragma unroll
    for (int s = 0; s < 8; ++s) {
        const int j = (wv << 9) | ((s >> 2) << 8) | (lane << 2) | (s & 3);
        rh[s] += sgn * (double)w[(size_t)j * IN_F + i];
    }
}

// TWO ROWS per 2-wave block, ROLE-SWAPPED (R13 structure): each wave owns the
// OUT-half of BOTH rows' residuals (rA[8], rB[8]) and the FULL v+kwta of ONE
// row (wave0=A, wave1=B). Both waves run a full kwta SIMULTANEOUSLY for
// different rows: zero parking (R10's 44%-busy cap) and zero duplication
// (R12's +22us issue). Register plan: persistent 48 VGPR (24 doubles), peak
// ~90 -> needs budget >64. amdgpu_waves_per_eu(1,4) caps occupancy at 4
// waves/EU (grid is exactly 4/SIMD) so VGPRs 65..128 cost NOTHING -> the
// allocator's spill-for-8-waves heuristic (R4/R13 failures) has no payoff.
template <int MODE>
__global__ __attribute__((amdgpu_flat_work_group_size(128, 128),
                          amdgpu_waves_per_eu(1, 4)))
void bmp_kernel(const float* __restrict__ x, const float* __restrict__ w,
                const float* __restrict__ wT, float* __restrict__ out, int rows) {
    __shared__ unsigned short act[2][IN_F + 8];
    __shared__ int cntS[2];
    __shared__ unsigned gu32[2][2];          // [row][wv] argmax merge (u32 key)
    __shared__ int gjw[2][2];                // [row][wv] argmax merge (index)
    __shared__ unsigned long long kx[2][2];  // rare exact cross-wave u64 merge
    __shared__ int axlist[2][16];            // [row] set-diff: idx (add) / ~idx (sub)
    __shared__ int axn[2];
    const int lane = threadIdx.x & 63;
    const int wv = threadIdx.x >> 6;
    const int rowA = blockIdx.x * 2;
    if (rowA >= rows) return;
    int rowB = rowA + 1;
    if (rowB >= rows) rowB = rowA;  // rows=4096 even: never taken
    const int myrow = wv ? rowB : rowA;

    // ---- each wave builds the active list of ITS row (wave-local ballots) ----
    {
        const float* xrow = x + (size_t)myrow * IN_F;
        int cnt = 0;
#pragma unroll
        for (int c = 0; c < IN_F / 64; ++c) {
            bool pbit = xrow[c * 64 + lane] != 0.0f;
            unsigned long long m = __ballot(pbit);
            int pre = __popcll(m & ((1ull << lane) - 1ull));
            if (pbit) act[wv][cnt + pre] = (unsigned short)(c * 64 + lane);
            cnt += __popcll(m);
        }
        if (lane < 2) act[wv][cnt + lane] = (unsigned short)IN_F;  // zero-row pad
        if (lane == 0) cntS[wv] = cnt;
    }
    __syncthreads();
    const int cntA = cntS[0], cntB = cntS[1];

    // ---- projection: own OUT-half of BOTH rows, software-pipelined ----
    double rA[8], rB[8];
#pragma unroll
    for (int s = 0; s < 8; ++s) { rA[s] = 0.0; rB[s] = 0.0; }
    const int base = (wv << 9) + (lane << 2);
    if constexpr (MODE == 1) {
#pragma unroll 1
        for (int rl = 0; rl < 2; ++rl) {  // static 2-iteration row loop
            double* r = rl ? rB : rA;
            const unsigned short* a = act[rl];
            const int cnt = rl ? cntB : cntA;
            const float* pa = wT + ((size_t)a[0] << 10) + base;
            const float* pb = wT + ((size_t)a[1] << 10) + base;
            float4 c0 = *(const float4*)pa, c1 = *(const float4*)(pa + 256);
            float4 c2 = *(const float4*)pb, c3 = *(const float4*)(pb + 256);
#pragma unroll 1
            for (int k = 0; k < cnt; k += 2) {
                float4 n0 = c0, n1 = c1, n2 = c2, n3 = c3;
                if (k + 2 < cnt) {  // act zero-padded -> a[k+3] always valid
                    const float* qa = wT + ((size_t)a[k + 2] << 10) + base;
                    const float* qb = wT + ((size_t)a[k + 3] << 10) + base;
                    n0 = *(const float4*)qa;  n1 = *(const float4*)(qa + 256);
                    n2 = *(const float4*)qb;  n3 = *(const float4*)(qb + 256);
                }
                r[0] += (double)c0.x + (double)c2.x;
                r[1] += (double)c0.y + (double)c2.y;
                r[2] += (double)c0.z + (double)c2.z;
                r[3] += (double)c0.w + (double)c2.w;
                r[4] += (double)c1.x + (double)c3.x;
                r[5] += (double)c1.y + (double)c3.y;
                r[6] += (double)c1.z + (double)c3.z;
                r[7] += (double)c1.w + (double)c3.w;
                c0 = n0; c1 = n1; c2 = n2; c3 = n3;
            }
        }
    } else {
#pragma unroll 1
        for (int k = 0; k < cntA; ++k) half_add0(rA, w, act[0][k], lane, wv);
#pragma unroll 1
        for (int k = 0; k < cntB; ++k) half_add0(rB, w, act[1][k], lane, wv);
    }
#pragma unroll
    for (int s = 0; s < 8; ++s) { rA[s] *= 2.0; rB[s] *= 2.0; }

    double vd[8];  // FULL v of OWN row
#pragma unroll
    for (int p = 0; p < 8; ++p) vd[p] = 0.0;

    unsigned encA = 0, encB = 0;  // per-lane 8-bit masks over own OUT-half slots
    unsigned selmask = 0;         // own row's final xr slots
    int O0 = -1, O1 = -1, O2 = -1, O3 = -1, O4 = -1, O5 = -1;  // own row's xr set

    // local half-argmax -> LDS (u32 fast path, exact u64 intra-wave fallback)
    auto amax_half = [&](const double* r, unsigned enc, int rsel) {
        unsigned k8[8];
#pragma unroll
        for (int s = 0; s < 8; ++s) {
            const unsigned key = hi_key(r[s]);
            k8[s] = (enc & (1u << s)) ? 0u : key;
        }
        unsigned lm = k8[0];
#pragma unroll
        for (int s = 1; s < 8; ++s) lm = k8[s] > lm ? k8[s] : lm;
        const unsigned g = wave_umax(lm);
        const unsigned long long tied = __ballot(lm == g);
        unsigned mm = 0;
#pragma unroll
        for (int s = 0; s < 8; ++s) mm |= (k8[s] == g) ? (1u << s) : 0u;
        const int L = (int)__ffsll((long long)tied) - 1;
        const unsigned mmL = (unsigned)__builtin_amdgcn_readlane((int)mm, L);
        int jw;
        if (__builtin_expect((__popcll(tied) == 1) && !(mmL & (mmL - 1)), 1)) {
            const int bi = __ffs(mmL) - 1;  // slot asc == j asc within lane
            jw = (wv << 9) | ((bi >> 2) << 8) | (L << 2) | (bi & 3);
        } else {  // exact intra-wave resolve among u32-tied candidates
            unsigned long long kb = 0;
#pragma unroll
            for (int s = 0; s < 8; ++s) {
                const int j = (wv << 9) | ((s >> 2) << 8) | (lane << 2) | (s & 3);
                const unsigned long long fk =
                    pack_key(r[s], 1023u ^ (unsigned)j, 1023ull);
                kb = (k8[s] == g && fk > kb) ? fk : kb;
            }
            const unsigned long long gk = wave_max_key(kb);
            jw = 1023 ^ (int)(gk & 1023ull);
        }
        if (lane == 0) {
            gu32[rsel][wv] = g;
            gjw[rsel][wv] = jw;
        }
    };

    // cross-wave merge (after B1); rare exact path has its own uniform barrier
    auto merge_row = [&](int rsel, const double* r, unsigned enc) -> int {
        const unsigned ga = gu32[rsel][0], gb = gu32[rsel][1];
        int bestj;
        if (__builtin_expect(ga != gb, 1)) {  // u32 strict order is f64-faithful
            bestj = (gb > ga) ? gjw[rsel][1] : gjw[rsel][0];
        } else {
            unsigned long long kb = 0;
#pragma unroll
            for (int s = 0; s < 8; ++s) {
                const int j = (wv << 9) | ((s >> 2) << 8) | (lane << 2) | (s & 3);
                const unsigned long long fk =
                    pack_key(r[s], 1023u ^ (unsigned)j, 1023ull);
                const bool cand = !(enc & (1u << s)) && hi_key(r[s]) == ga;
                kb = (cand && fk > kb) ? fk : kb;
            }
            const unsigned long long wm = wave_max_key(kb);
            if (lane == 0) kx[rsel][wv] = wm;
            __syncthreads();
            const unsigned long long A = kx[rsel][0], B = kx[rsel][1];
            bestj = 1023 ^ (int)((A > B ? A : B) & 1023ull);
        }
        return __builtin_amdgcn_readfirstlane(bestj);
    };

#pragma unroll 1
    for (int t = 0; t < K_ACTIVE; ++t) {
        // ---- both waves: half-argmax for BOTH rows (2 independent chains) ----
        amax_half(rA, encA, 0);
        amax_half(rB, encB, 1);
        __syncthreads();  // B1
        const int bestjA = merge_row(0, rA, encA);
        const int bestjB = merge_row(1, rB, encB);
        if ((bestjA >> 9) == wv && ((bestjA >> 2) & 63) == lane)
            encA |= 1u << ((((bestjA >> 8) & 1) << 2) | (bestjA & 3));
        if ((bestjB >> 9) == wv && ((bestjB >> 2) & 63) == lane)
            encB |= 1u << ((((bestjB >> 8) & 1) << 2) | (bestjB & 3));

        // ---- OWN row: v += W[bestj], full kwta, build own set-diff list ----
        {
            const int bj = wv ? bestjB : bestjA;
            const float* wr = w + ((size_t)bj << 9) + (lane << 2);
            const float4 f0 = *(const float4*)wr;
            const float4 f1 = *(const float4*)(wr + 256);
            vd[0] += (double)f0.x;  vd[1] += (double)f0.y;
            vd[2] += (double)f0.z;  vd[3] += (double)f0.w;
            vd[4] += (double)f1.x;  vd[5] += (double)f1.y;
            vd[6] += (double)f1.z;  vd[7] += (double)f1.w;

            int N[6];
            unsigned kk[8];  // transient u32
#pragma unroll
            for (int p = 0; p < 8; ++p) kk[p] = hi_key(vd[p]);
#pragma unroll
            for (int s2 = 0; s2 < K_IN; ++s2) {
                unsigned lm = kk[0];
#pragma unroll
                for (int p = 1; p < 8; ++p) lm = kk[p] > lm ? kk[p] : lm;
                const unsigned g2 = wave_umax(lm);
                const unsigned long long tied2 = __ballot(lm == g2);
                unsigned mm2 = 0;
#pragma unroll
                for (int p = 0; p < 8; ++p) mm2 |= (kk[p] == g2) ? (1u << p) : 0u;
                const int L2 = (int)__ffsll((long long)tied2) - 1;
                const unsigned mmL2 =
                    (unsigned)__builtin_amdgcn_readlane((int)mm2, L2);
                int n;
                if (__builtin_expect((__popcll(tied2) == 1) && !(mmL2 & (mmL2 - 1)),
                                     1)) {
                    const int bp = __ffs(mmL2) - 1;
                    n = ((bp >> 2) << 8) | (L2 << 2) | (bp & 3);
#pragma unroll
                    for (int p = 0; p < 8; ++p) kk[p] = (kk[p] == g2) ? 0u : kk[p];
                } else {  // exact resolve among u32-tied candidates
                    unsigned long long kb = 0;
#pragma unroll
                    for (int p = 0; p < 8; ++p) {
                        const int i = ((p >> 2) << 8) | (lane << 2) | (p & 3);
                        const unsigned long long fk =
                            pack_key(vd[p], 511u ^ (unsigned)i, 511ull);
                        kb = (kk[p] == g2 && fk > kb) ? fk : kb;
                    }
                    const unsigned long long gk = wave_max_key(kb);
                    n = 511 ^ (int)(gk & 511ull);
                    const int ln = (n >> 2) & 63;
                    const int bp = (((n >> 8) & 1) << 2) | (n & 3);
#pragma unroll
                    for (int p = 0; p < 8; ++p)
                        kk[p] = (lane == ln && p == bp) ? 0u : kk[p];
                }
                N[s2] = __builtin_amdgcn_readfirstlane(n);
            }
            if (t == K_ACTIVE - 1) {
                selmask = 0;  // cleared keys are 0 (0 unreachable for real values)
#pragma unroll
                for (int p = 0; p < 8; ++p) selmask |= (kk[p] == 0u) ? (1u << p) : 0u;
            }

            // build own row's set-diff list (lane0, LDS-resident -> rule #20 safe)
            if (lane == 0) {
                int n2 = 0;
                if (t == 0) {
#pragma unroll
                    for (int b = 0; b < 6; ++b) axlist[wv][n2++] = ~N[b];  // subtract
                } else if (t < K_ACTIVE - 1) {
#pragma unroll
                    for (int a2 = 0; a2 < 6; ++a2) {
                        const int o = (a2 == 0) ? O0 : (a2 == 1) ? O1 : (a2 == 2) ? O2
                                      : (a2 == 3) ? O3 : (a2 == 4) ? O4 : O5;
                        const bool stay = (o == N[0]) | (o == N[1]) | (o == N[2]) |
                                          (o == N[3]) | (o == N[4]) | (o == N[5]);
                        if (!stay) axlist[wv][n2++] = o;  // add back
                    }
#pragma unroll
                    for (int b = 0; b < 6; ++b) {
                        const int nn = N[b];
                        const bool was = (nn == O0) | (nn == O1) | (nn == O2) |
                                         (nn == O3) | (nn == O4) | (nn == O5);
                        if (!was) axlist[wv][n2++] = ~nn;  // subtract
                    }
                }
                axn[wv] = n2;
            }
            O0 = N[0]; O1 = N[1]; O2 = N[2]; O3 = N[3]; O4 = N[4]; O5 = N[5];
        }
        __syncthreads();  // B2: both rows' lists -> both waves

        // ---- pipelined set-diff axpy on own halves of BOTH rows ----
#pragma unroll
        for (int rl = 0; rl < 2; ++rl) {
            double* r = rl ? rB : rA;
            const int nax = axn[rl];  // uniform
            if (nax > 0) {
                if constexpr (MODE == 1) {
                    int e0 = axlist[rl][0];
                    const int i0 = (e0 < 0) ? ~e0 : e0;
                    const float* p = wT + ((size_t)i0 << 10) + base;
                    float4 A0 = *(const float4*)p;
                    float4 A1 = *(const float4*)(p + 256);
#pragma unroll 1
                    for (int k = 0; k < nax; ++k) {
                        float4 B0 = A0, B1 = A1;
                        int e1 = 0;
                        if (k + 1 < nax) {
                            e1 = axlist[rl][k + 1];
                            const int i1 = (e1 < 0) ? ~e1 : e1;
                            const float* q = wT + ((size_t)i1 << 10) + base;
                            B0 = *(const float4*)q;
                            B1 = *(const float4*)(q + 256);
                        }
                        const double sg = (e0 < 0) ? -1.0 : 1.0;
                        r[0] += sg * (double)A0.x;  r[1] += sg * (double)A0.y;
                        r[2] += sg * (double)A0.z;  r[3] += sg * (double)A0.w;
                        r[4] += sg * (double)A1.x;  r[5] += sg * (double)A1.y;
                        r[6] += sg * (double)A1.z;  r[7] += sg * (double)A1.w;
                        A0 = B0; A1 = B1; e0 = e1;
                    }
                } else {
#pragma unroll 1
                    for (int k = 0; k < nax; ++k) {
                        const int e = axlist[rl][k];
                        const int i = (e < 0) ? ~e : e;
                        half_axpy0(r, w, i, (e < 0) ? -1.0 : 1.0, lane, wv);
                    }
                }
            }
        }
    }

    // ---- outputs: encoded halves of both rows; xr of own row ----
    {
        float* oeA = out + (size_t)rowA * OUT_F + (wv << 9) + (lane << 2);
#pragma unroll
        for (int c = 0; c < 2; ++c) {
            float4 v;
            v.x = (encA & (1u << (4 * c + 0))) ? 1.0f : 0.0f;
            v.y = (encA & (1u << (4 * c + 1))) ? 1.0f : 0.0f;
            v.z = (encA & (1u << (4 * c + 2))) ? 1.0f : 0.0f;
            v.w = (encA & (1u << (4 * c + 3))) ? 1.0f : 0.0f;
            *(float4*)(oeA + (c << 8)) = v;
        }
        float* oeB = out + (size_t)rowB * OUT_F + (wv << 9) + (lane << 2);
#pragma unroll
        for (int c = 0; c < 2; ++c) {
            float4 v;
            v.x = (encB & (1u << (4 * c + 0))) ? 1.0f : 0.0f;
            v.y = (encB & (1u << (4 * c + 1))) ? 1.0f : 0.0f;
            v.z = (encB & (1u << (4 * c + 2))) ? 1.0f : 0.0f;
            v.w = (encB & (1u << (4 * c + 3))) ? 1.0f : 0.0f;
            *(float4*)(oeB + (c << 8)) = v;
        }
        float* ox = out + (size_t)rows * OUT_F + (size_t)myrow * IN_F + (lane << 2);
#pragma unroll
        for (int c = 0; c < 2; ++c) {
            float4 v;
            v.x = (selmask & (1u << (4 * c + 0))) ? 1.0f : 0.0f;
            v.y = (selmask & (1u << (4 * c + 1))) ? 1.0f : 0.0f;
            v.z = (selmask & (1u << (4 * c + 2))) ? 1.0f : 0.0f;
            v.w = (selmask & (1u << (4 * c + 3))) ? 1.0f : 0.0f;
            *(float4*)(ox + (c << 8)) = v;
        }
    }
}

extern "C" void kernel_launch(void* const* d_in, const int* in_sizes, int n_in,
                              void* d_out, int out_size, void* d_ws, size_t ws_size,
                              hipStream_t stream) {
    const float* x = (const float*)d_in[0];
    const float* w = (const float*)d_in[1];
    float* out = (float*)d_out;
    const int rows = in_sizes[0] / IN_F;  // 4096

    const size_t need_f = (size_t)(IN_F + 1) * OUT_F * sizeof(float);  // 2.1 MB
    const int blocks = (rows + 1) / 2;  // 2 rows per 2-wave block

    if (d_ws != nullptr && ws_size >= need_f) {
        float* wT = (float*)d_ws;
        transpose_w_kernel<<<dim3(IN_F / 32, OUT_F / 32), 256, 0, stream>>>(w, wT);
        zero_row_f_kernel<<<OUT_F / 256, 256, 0, stream>>>(wT);
        bmp_kernel<1><<<blocks, 128, 0, stream>>>(x, w, wT, out, rows);
    } else {
        bmp_kernel<0><<<blocks, 128, 0, stream>>>(x, w, nullptr, out, rows);
    }
}